// Round 6
// baseline (850.561 us; speedup 1.0000x reference)
//
#include <hip/hip_runtime.h>
#include <math.h>

#define NN 10000
#define NE 160000
#define NB 4
#define NH 4
#define ND 256
#define NT (NN * 16)        // (n,b,h) triples
#define NM 40000            // GEMM rows (b*NN+n)

typedef _Float16 f16;
typedef _Float16 half8 __attribute__((ext_vector_type(8)));
typedef float f32x4 __attribute__((ext_vector_type(4)));

union H4 { uint2 u; f16 h[4]; };

__device__ __forceinline__ void gload_lds16(const void* g, void* l) {
  __builtin_amdgcn_global_load_lds((const __attribute__((address_space(1))) void*)g,
                                   (__attribute__((address_space(3))) void*)l, 16, 0, 0);
}

// ---------------- CSR build ----------------
__global__ __launch_bounds__(256) void k_deg(const int* __restrict__ dst, int* __restrict__ deg) {
  int e = blockIdx.x * 256 + threadIdx.x;
  if (e < NE) atomicAdd(&deg[dst[e]], 1);
}

__global__ __launch_bounds__(1024) void k_scan(const int* __restrict__ deg, int* __restrict__ offs) {
  __shared__ int tmp[1024];
  __shared__ int carry_s;
  if (threadIdx.x == 0) carry_s = 0;
  __syncthreads();
  for (int base = 0; base < NN; base += 1024) {
    int i = base + (int)threadIdx.x;
    int v = (i < NN) ? deg[i] : 0;
    int c0 = carry_s;
    tmp[threadIdx.x] = v;
    __syncthreads();
    for (int s = 1; s < 1024; s <<= 1) {
      int add = (threadIdx.x >= (unsigned)s) ? tmp[threadIdx.x - s] : 0;
      __syncthreads();
      tmp[threadIdx.x] += add;
      __syncthreads();
    }
    if (i < NN) offs[i] = c0 + tmp[threadIdx.x] - v;   // exclusive
    int tot = tmp[1023];
    __syncthreads();
    if (threadIdx.x == 0) carry_s = c0 + tot;
    __syncthreads();
  }
  if (threadIdx.x == 0) offs[NN] = carry_s;
}

__global__ __launch_bounds__(256) void k_scatter(const int* __restrict__ src, const int* __restrict__ dst,
                                                 const float* __restrict__ w, const int* __restrict__ offs,
                                                 int* __restrict__ cursor, int* __restrict__ csr_src,
                                                 int* __restrict__ csr_dst, float* __restrict__ csr_w) {
  int e = blockIdx.x * 256 + threadIdx.x;
  if (e < NE) {
    int d = dst[e];
    int slot = offs[d] + atomicAdd(&cursor[d], 1);
    csr_src[slot] = src[e];
    csr_dst[slot] = d;
    csr_w[slot] = w[e];
  }
}

// ---------------- converters ----------------
__global__ __launch_bounds__(256) void k_cvt_sol(const float* __restrict__ sol, f16* __restrict__ solh) {
  int i = blockIdx.x * 256 + threadIdx.x;
  int row = i >> 6, q = i & 63;
  int k = q << 2;
  const float* s = (k < 128) ? (sol + (size_t)row * 128 + k)
                             : (sol + (size_t)(NM + row) * 128 + (k - 128));
  float4 v = *(const float4*)s;
  H4 h;
  h.h[0] = (f16)v.x; h.h[1] = (f16)v.y; h.h[2] = (f16)v.z; h.h[3] = (f16)v.w;
  *(uint2*)(solh + (size_t)row * 256 + k) = h.u;
}

__global__ __launch_bounds__(256) void k_cvt4(const float* __restrict__ in, f16* __restrict__ out, int n4) {
  int i = blockIdx.x * 256 + threadIdx.x;
  if (i < n4) {
    float4 v = *(const float4*)(in + (size_t)i * 4);
    H4 h;
    h.h[0] = (f16)v.x; h.h[1] = (f16)v.y; h.h[2] = (f16)v.z; h.h[3] = (f16)v.w;
    *(uint2*)(out + (size_t)i * 4) = h.u;
  }
}

// ---------------- weight fusion ----------------
__global__ __launch_bounds__(256) void k_fuse_wh(const float* __restrict__ fc_w, const float* __restrict__ ofc_w,
                                                 f16* __restrict__ fwh) {
  int r = blockIdx.x;        // 0..255 = h*64+o
  int d = threadIdx.x;       // 0..255
  int h = r >> 6, o = r & 63;
  float acc = 0.f;
  for (int f = 0; f < 64; ++f)
    acc = fmaf(ofc_w[(o << 6) + f], fc_w[(((h << 6) + f) << 8) + d], acc);
  fwh[(r << 8) + d] = (f16)acc;
}

__global__ __launch_bounds__(256) void k_fuse_attn(const float* __restrict__ fc_w,
                                                   const float* __restrict__ al, const float* __restrict__ ar,
                                                   float* __restrict__ alf) {
  int r = blockIdx.x;        // 0..7
  int d = threadIdx.x;
  int h = r & 3;
  const float* a = (r < 4) ? al : ar;
  float acc = 0.f;
  for (int f = 0; f < 64; ++f)
    acc = fmaf(a[(h << 6) + f], fc_w[(((h << 6) + f) << 8) + d], acc);
  alf[(r << 8) + d] = acc;
}

// ---------------- MFMA fp16 GEMM ----------------
// PERM=0: out[ra][col] fp32/fp16 per OUTH. PERM=2: featW_t[(b*4+h)][n][o] fp16.
template<int PERM, int OUTH>
__global__ __launch_bounds__(256) void k_gemm_f16(
    const f16* __restrict__ A, int lda, int K,
    const f16* __restrict__ W,
    const float* __restrict__ bias,
    void* __restrict__ outp, int ldo)
{
  __shared__ __align__(16) f16 As[64 * 32];
  __shared__ __align__(16) f16 Bs[128 * 32];
  const int tid = threadIdx.x;
  const int lane = tid & 63;
  const int w = tid >> 6;
  const int wr = w >> 1, wc = w & 1;
  const int ra0 = blockIdx.x * 64;
  const int c0 = blockIdx.y * 128;
  const int l2 = lane >> 2;
  const int lk8 = (lane & 3) * 8;

  f32x4 acc[2][4];
#pragma unroll
  for (int mr = 0; mr < 2; ++mr)
#pragma unroll
    for (int nr = 0; nr < 4; ++nr) acc[mr][nr] = (f32x4)0.f;

  const int fr = lane & 15;
  const int fg = (lane >> 4) * 8;

  for (int k0 = 0; k0 < K; k0 += 32) {
    gload_lds16(A + (size_t)(ra0 + 16 * w + l2) * lda + k0 + lk8, As + w * 512);
    gload_lds16(W + (size_t)(c0 + 32 * w + l2) * K + k0 + lk8, Bs + w * 1024);
    gload_lds16(W + (size_t)(c0 + 32 * w + 16 + l2) * K + k0 + lk8, Bs + w * 1024 + 512);
    __syncthreads();

    half8 af[2], bf[4];
#pragma unroll
    for (int mr = 0; mr < 2; ++mr)
      af[mr] = *(const half8*)(As + (wr * 32 + mr * 16 + fr) * 32 + fg);
#pragma unroll
    for (int nr = 0; nr < 4; ++nr)
      bf[nr] = *(const half8*)(Bs + (wc * 64 + nr * 16 + fr) * 32 + fg);
#pragma unroll
    for (int mr = 0; mr < 2; ++mr)
#pragma unroll
      for (int nr = 0; nr < 4; ++nr)
        acc[mr][nr] = __builtin_amdgcn_mfma_f32_16x16x32_f16(af[mr], bf[nr], acc[mr][nr], 0, 0, 0);
    __syncthreads();
  }

  const int r0 = (lane >> 4) * 4;
#pragma unroll
  for (int nr = 0; nr < 4; ++nr) {
    int col = c0 + wc * 64 + nr * 16 + fr;
    float bv = bias ? bias[col] : 0.f;
    int h = col >> 6, o = col & 63;
#pragma unroll
    for (int mr = 0; mr < 2; ++mr) {
      f32x4 v = acc[mr][nr];
#pragma unroll
      for (int r = 0; r < 4; ++r) {
        int ra = ra0 + wr * 32 + mr * 16 + r0 + r;
        float val = v[r] + bv;
        if (PERM == 2) {
          int n = ra % NN, b = ra / NN;
          ((f16*)outp)[(((size_t)(b * 4 + h) * NN + n) << 6) + o] = (f16)val;
        } else if (OUTH) {
          ((f16*)outp)[(size_t)ra * ldo + col] = (f16)val;
        } else {
          ((float*)outp)[(size_t)ra * ldo + col] = val;
        }
      }
    }
  }
}

// ---------------- el/er (bh-major transposed out) ----------------
__global__ __launch_bounds__(256) void k_eler3h(
    const f16* __restrict__ xh, int lda,
    const float* __restrict__ alf, float* __restrict__ el_t, float* __restrict__ er_t)
{
  int wid = threadIdx.x >> 6, lane = threadIdx.x & 63;
  int ra = blockIdx.x * 4 + wid;        // b*NN+n
  int k0 = lane << 2;
  H4 hv;
  hv.u = *(const uint2*)(xh + (size_t)ra * lda + k0);
  float x0 = (float)hv.h[0], x1 = (float)hv.h[1], x2 = (float)hv.h[2], x3 = (float)hv.h[3];
  int n = ra % NN, b = ra / NN;
#pragma unroll
  for (int oi = 0; oi < 8; ++oi) {
    float4 av = *(const float4*)(alf + (oi << 8) + k0);
    float s = x0 * av.x + x1 * av.y + x2 * av.z + x3 * av.w;
#pragma unroll
    for (int k = 32; k; k >>= 1) s += __shfl_xor(s, k);
    if (lane == 0) {
      int h = oi & 3;
      size_t idx = (size_t)(b * 4 + h) * NN + n;
      if (oi < 4) el_t[idx] = s;
      else        er_t[idx] = s;
    }
  }
}

// ---------------- edge-parallel softmax (atomics, no reductions) ----------------
// grid (NE/256, 16): thread = (slot, bh). Gathers hit 40KB bh-slices (L1/L2).
__global__ __launch_bounds__(256) void k_smax(
    const int* __restrict__ csr_src, const int* __restrict__ csr_dst, const float* __restrict__ csr_w,
    const float* __restrict__ el_t, const float* __restrict__ er_t, unsigned* __restrict__ mkey)
{
  int slot = blockIdx.x * 256 + threadIdx.x;
  int bh = blockIdx.y;
  int src = csr_src[slot], dst = csr_dst[slot];
  float x = el_t[(size_t)bh * NN + src] + er_t[(size_t)bh * NN + dst];
  x = (x > 0.f) ? x : 0.1f * x;
  float s = x * csr_w[slot];
  int i = __float_as_int(s);
  unsigned k = (i < 0) ? ~(unsigned)i : ((unsigned)i | 0x80000000u);
  atomicMax(&mkey[(size_t)bh * NN + dst], k);
}

__global__ __launch_bounds__(256) void k_sexp(
    const int* __restrict__ csr_src, const int* __restrict__ csr_dst, const float* __restrict__ csr_w,
    const float* __restrict__ el_t, const float* __restrict__ er_t,
    const unsigned* __restrict__ mkey, float* __restrict__ ex_t, float* __restrict__ sbuf)
{
  int slot = blockIdx.x * 256 + threadIdx.x;
  int bh = blockIdx.y;
  int src = csr_src[slot], dst = csr_dst[slot];
  float x = el_t[(size_t)bh * NN + src] + er_t[(size_t)bh * NN + dst];
  x = (x > 0.f) ? x : 0.1f * x;
  float s = x * csr_w[slot];
  unsigned k = mkey[(size_t)bh * NN + dst];
  int mi = (k & 0x80000000u) ? (int)(k & 0x7fffffffu) : ~(int)k;
  float ex = __expf(s - __int_as_float(mi));
  ex_t[(size_t)bh * NE + slot] = ex;                 // coalesced
  atomicAdd(&sbuf[(size_t)bh * NN + dst], ex);
}

// ---------------- aggregate only: bh-split, wave-per-node ----------------
// blockIdx.x = chunk*16 + bh -> XCD = bid%8 = bh%8: per-XCD L2 keeps bh slices hot.
// lane = es*16+cg: es = edge slot (4-way edge ILP), cg = 4-channel group (uint2 loads).
__global__ __launch_bounds__(256) void k_edge5(
    const f16* __restrict__ featW_t, const float* __restrict__ ex_t, const float* __restrict__ sbuf,
    const int* __restrict__ csr_src, const int* __restrict__ offs,
    const float* __restrict__ b2, f16* __restrict__ outh)
{
  __shared__ float2 as_[4][64];        // {alpha, bitcast(src)} per wave
  const int t = threadIdx.x;
  const int w = t >> 6, lane = t & 63;
  const int bh = blockIdx.x & 15;
  const int n = (blockIdx.x >> 4) * 4 + w;
  const int s0 = offs[n], s1 = offs[n + 1];
  const f16* fW = featW_t + ((size_t)bh * NN << 6);
  const float* exs = ex_t + (size_t)bh * NE;
  const int es = lane >> 4;            // 0..3 edge slot
  const int cg = lane & 15;            // 0..15 channel group (4 ch)

  float a0 = 0.f, a1 = 0.f, a2 = 0.f, a3 = 0.f;

  for (int c0 = s0; c0 < s1; c0 += 64) {
    const int csz = min(64, s1 - c0);
    float alpha = 0.f;
    int src = 0;
    if (lane < csz) {                  // both loads coalesced (256B/wave)
      src = csr_src[c0 + lane];
      alpha = exs[c0 + lane];
    }
    as_[w][lane] = make_float2(alpha, __int_as_float(src));
    for (int e = 0; e < csz; e += 4) {
      float2 pp = as_[w][e + es];      // broadcast within each 16-lane group
      int sn = __float_as_int(pp.y);
      H4 fv;
      fv.u = *(const uint2*)(fW + ((size_t)sn << 6) + (cg << 2));
      float al = pp.x;
      a0 = fmaf(al, (float)fv.h[0], a0);
      a1 = fmaf(al, (float)fv.h[1], a1);
      a2 = fmaf(al, (float)fv.h[2], a2);
      a3 = fmaf(al, (float)fv.h[3], a3);
    }
  }
  // cross-edge-slot reduction (es bits = lane bits 4,5)
#pragma unroll
  for (int k = 16; k <= 32; k <<= 1) {
    a0 += __shfl_xor(a0, k);
    a1 += __shfl_xor(a1, k);
    a2 += __shfl_xor(a2, k);
    a3 += __shfl_xor(a3, k);
  }
  if (lane < 16) {
    float invs = (s1 > s0) ? 1.f / sbuf[(size_t)bh * NN + n] : 0.f;
    const float4 bv = *(const float4*)(b2 + (cg << 2));
    H4 o;
    o.h[0] = (f16)fmaxf(fmaf(a0, invs, bv.x), 0.f);
    o.h[1] = (f16)fmaxf(fmaf(a1, invs, bv.y), 0.f);
    o.h[2] = (f16)fmaxf(fmaf(a2, invs, bv.z), 0.f);
    o.h[3] = (f16)fmaxf(fmaf(a3, invs, bv.w), 0.f);
    const int b = bh >> 2, h = bh & 3;
    *(uint2*)(outh + (((size_t)b * NN + n) << 9) + (h << 6) + (cg << 2)) = o.u;
  }
}

// ---------------- launch ----------------
extern "C" void kernel_launch(void* const* d_in, const int* in_sizes, int n_in,
                              void* d_out, int out_size, void* d_ws, size_t ws_size,
                              hipStream_t stream) {
  const float* sol    = (const float*)d_in[0];
  const float* w      = (const float*)d_in[1];
  const float* fc_w   = (const float*)d_in[2];
  const float* attn_l = (const float*)d_in[3];
  const float* attn_r = (const float*)d_in[4];
  const float* ofc_w  = (const float*)d_in[5];
  const float* ofc_b  = (const float*)d_in[6];
  const float* mlp_w  = (const float*)d_in[7];
  const float* mlp_b  = (const float*)d_in[8];
  const int*   d_src  = (const int*)d_in[9];
  const int*   d_dst  = (const int*)d_in[10];
  float* out = (float*)d_out;

  char* p = (char*)d_ws;
  auto alloc = [&](size_t bytes) { char* r = p; p += (bytes + 255) & ~(size_t)255; return r; };
  f16*   solh    = (f16*)alloc((size_t)NM * 256 * 2);
  f16*   out01h  = (f16*)alloc((size_t)NM * 512 * 2);
  f16*   featWt  = (f16*)alloc((size_t)NT * 64 * 2);       // [16][NN][64]
  f16*   fwh     = (f16*)alloc((size_t)ND * ND * 2);
  f16*   mlph    = (f16*)alloc((size_t)ND * 512 * 2);
  float* el_t    = (float*)alloc((size_t)NT * 4);          // [16][NN]
  float* er_t    = (float*)alloc((size_t)NT * 4);
  float* alf     = (float*)alloc((size_t)8 * ND * 4);
  float* ex_t    = (float*)alloc((size_t)16 * NE * 4);     // [16][NE] 10.24MB
  unsigned* mkey = (unsigned*)alloc((size_t)NT * 4);       // [16][NN]
  float* sbuf    = (float*)alloc((size_t)NT * 4);          // [16][NN]
  int*   deg     = (int*)alloc((size_t)(NN + 1) * 4);
  int*   offs    = (int*)alloc((size_t)(NN + 1) * 4);
  int*   cursor  = (int*)alloc((size_t)NN * 4);
  int*   csr_src = (int*)alloc((size_t)NE * 4);
  int*   csr_dst = (int*)alloc((size_t)NE * 4);
  float* csr_w   = (float*)alloc((size_t)NE * 4);
  if ((size_t)(p - (char*)d_ws) > ws_size) return;

  hipMemsetAsync(deg, 0, (size_t)NN * 4, stream);
  hipMemsetAsync(cursor, 0, (size_t)NN * 4, stream);
  k_deg<<<NE / 256, 256, 0, stream>>>(d_dst, deg);
  k_scan<<<1, 1024, 0, stream>>>(deg, offs);
  k_scatter<<<NE / 256, 256, 0, stream>>>(d_src, d_dst, w, offs, cursor, csr_src, csr_dst, csr_w);

  k_cvt_sol<<<NM * 64 / 256, 256, 0, stream>>>(sol, solh);
  k_cvt4<<<(ND * 512 / 4 + 255) / 256, 256, 0, stream>>>(mlp_w, mlph, ND * 512 / 4);

  for (int l = 0; l < 2; ++l) {
    const float* fcl = fc_w + (size_t)l * ND * ND;
    k_fuse_wh<<<256, 256, 0, stream>>>(fcl, ofc_w + (size_t)l * 64 * 64, fwh);
    k_fuse_attn<<<8, 256, 0, stream>>>(fcl, attn_l + (size_t)l * NH * 64, attn_r + (size_t)l * NH * 64, alf);
    const f16* Ah = (l == 0) ? solh : out01h;
    int lda = (l == 0) ? 256 : 512;
    k_gemm_f16<2, 1><<<dim3(NM / 64, ND / 128), 256, 0, stream>>>(
        Ah, lda, 256, fwh, nullptr, featWt, 64);
    k_eler3h<<<NM / 4, 256, 0, stream>>>(Ah, lda, alf, el_t, er_t);
    hipMemsetAsync(mkey, 0, (size_t)NT * 4, stream);
    hipMemsetAsync(sbuf, 0, (size_t)NT * 4, stream);
    k_smax<<<dim3(NE / 256, 16), 256, 0, stream>>>(csr_src, csr_dst, csr_w, el_t, er_t, mkey);
    k_sexp<<<dim3(NE / 256, 16), 256, 0, stream>>>(csr_src, csr_dst, csr_w, el_t, er_t, mkey, ex_t, sbuf);
    k_edge5<<<(NN / 4) * 16, 256, 0, stream>>>(featWt, ex_t, sbuf, csr_src, offs,
                                               ofc_b + (size_t)l * 64, out01h + (l == 0 ? 0 : 256));
  }

  k_gemm_f16<0, 0><<<dim3(NM / 64, ND / 128), 256, 0, stream>>>(
      out01h, 512, 512, mlph, mlp_b, out, 256);
}

// Round 7
// 341.254 us; speedup vs baseline: 2.4925x; 2.4925x over previous
//
#include <hip/hip_runtime.h>
#include <math.h>

#define NN 10000
#define NE 160000
#define NB 4
#define NH 4
#define ND 256
#define NT (NN * 16)        // (n,b,h) triples
#define NM 40000            // GEMM rows (b*NN+n)

typedef _Float16 f16;
typedef _Float16 half8 __attribute__((ext_vector_type(8)));
typedef float f32x4 __attribute__((ext_vector_type(4)));

union H4 { uint2 u; f16 h[4]; };

__device__ __forceinline__ void gload_lds16(const void* g, void* l) {
  __builtin_amdgcn_global_load_lds((const __attribute__((address_space(1))) void*)g,
                                   (__attribute__((address_space(3))) void*)l, 16, 0, 0);
}

// ---------------- CSR build ----------------
__global__ __launch_bounds__(256) void k_deg(const int* __restrict__ dst, int* __restrict__ deg) {
  int e = blockIdx.x * 256 + threadIdx.x;
  if (e < NE) atomicAdd(&deg[dst[e]], 1);
}

__global__ __launch_bounds__(1024) void k_scan(const int* __restrict__ deg, int* __restrict__ offs) {
  __shared__ int tmp[1024];
  __shared__ int carry_s;
  if (threadIdx.x == 0) carry_s = 0;
  __syncthreads();
  for (int base = 0; base < NN; base += 1024) {
    int i = base + (int)threadIdx.x;
    int v = (i < NN) ? deg[i] : 0;
    int c0 = carry_s;
    tmp[threadIdx.x] = v;
    __syncthreads();
    for (int s = 1; s < 1024; s <<= 1) {
      int add = (threadIdx.x >= (unsigned)s) ? tmp[threadIdx.x - s] : 0;
      __syncthreads();
      tmp[threadIdx.x] += add;
      __syncthreads();
    }
    if (i < NN) offs[i] = c0 + tmp[threadIdx.x] - v;   // exclusive
    int tot = tmp[1023];
    __syncthreads();
    if (threadIdx.x == 0) carry_s = c0 + tot;
    __syncthreads();
  }
  if (threadIdx.x == 0) offs[NN] = carry_s;
}

__global__ __launch_bounds__(256) void k_scatter(const int* __restrict__ src, const int* __restrict__ dst,
                                                 const float* __restrict__ w, const int* __restrict__ offs,
                                                 int* __restrict__ cursor, int* __restrict__ csr_src,
                                                 float* __restrict__ csr_w) {
  int e = blockIdx.x * 256 + threadIdx.x;
  if (e < NE) {
    int d = dst[e];
    int slot = offs[d] + atomicAdd(&cursor[d], 1);
    csr_src[slot] = src[e];
    csr_w[slot] = w[e];
  }
}

// ---------------- converters ----------------
__global__ __launch_bounds__(256) void k_cvt_sol(const float* __restrict__ sol, f16* __restrict__ solh) {
  int i = blockIdx.x * 256 + threadIdx.x;
  int row = i >> 6, q = i & 63;
  int k = q << 2;
  const float* s = (k < 128) ? (sol + (size_t)row * 128 + k)
                             : (sol + (size_t)(NM + row) * 128 + (k - 128));
  float4 v = *(const float4*)s;
  H4 h;
  h.h[0] = (f16)v.x; h.h[1] = (f16)v.y; h.h[2] = (f16)v.z; h.h[3] = (f16)v.w;
  *(uint2*)(solh + (size_t)row * 256 + k) = h.u;
}

__global__ __launch_bounds__(256) void k_cvt4(const float* __restrict__ in, f16* __restrict__ out, int n4) {
  int i = blockIdx.x * 256 + threadIdx.x;
  if (i < n4) {
    float4 v = *(const float4*)(in + (size_t)i * 4);
    H4 h;
    h.h[0] = (f16)v.x; h.h[1] = (f16)v.y; h.h[2] = (f16)v.z; h.h[3] = (f16)v.w;
    *(uint2*)(out + (size_t)i * 4) = h.u;
  }
}

// ---------------- weight fusion ----------------
__global__ __launch_bounds__(256) void k_fuse_wh(const float* __restrict__ fc_w, const float* __restrict__ ofc_w,
                                                 f16* __restrict__ fwh) {
  int r = blockIdx.x;        // 0..255 = h*64+o
  int d = threadIdx.x;       // 0..255
  int h = r >> 6, o = r & 63;
  float acc = 0.f;
  for (int f = 0; f < 64; ++f)
    acc = fmaf(ofc_w[(o << 6) + f], fc_w[(((h << 6) + f) << 8) + d], acc);
  fwh[(r << 8) + d] = (f16)acc;
}

__global__ __launch_bounds__(256) void k_fuse_attn(const float* __restrict__ fc_w,
                                                   const float* __restrict__ al, const float* __restrict__ ar,
                                                   float* __restrict__ alf) {
  int r = blockIdx.x;        // 0..7
  int d = threadIdx.x;
  int h = r & 3;
  const float* a = (r < 4) ? al : ar;
  float acc = 0.f;
  for (int f = 0; f < 64; ++f)
    acc = fmaf(a[(h << 6) + f], fc_w[(((h << 6) + f) << 8) + d], acc);
  alf[(r << 8) + d] = acc;
}

// ---------------- MFMA fp16 GEMM ----------------
// PERM=0: out[ra][col] fp32/fp16 per OUTH. PERM=2: featW_t[(b*4+h)][n][o] fp16.
template<int PERM, int OUTH>
__global__ __launch_bounds__(256) void k_gemm_f16(
    const f16* __restrict__ A, int lda, int K,
    const f16* __restrict__ W,
    const float* __restrict__ bias,
    void* __restrict__ outp, int ldo)
{
  __shared__ __align__(16) f16 As[64 * 32];
  __shared__ __align__(16) f16 Bs[128 * 32];
  const int tid = threadIdx.x;
  const int lane = tid & 63;
  const int w = tid >> 6;
  const int wr = w >> 1, wc = w & 1;
  const int ra0 = blockIdx.x * 64;
  const int c0 = blockIdx.y * 128;
  const int l2 = lane >> 2;
  const int lk8 = (lane & 3) * 8;

  f32x4 acc[2][4];
#pragma unroll
  for (int mr = 0; mr < 2; ++mr)
#pragma unroll
    for (int nr = 0; nr < 4; ++nr) acc[mr][nr] = (f32x4)0.f;

  const int fr = lane & 15;
  const int fg = (lane >> 4) * 8;

  for (int k0 = 0; k0 < K; k0 += 32) {
    gload_lds16(A + (size_t)(ra0 + 16 * w + l2) * lda + k0 + lk8, As + w * 512);
    gload_lds16(W + (size_t)(c0 + 32 * w + l2) * K + k0 + lk8, Bs + w * 1024);
    gload_lds16(W + (size_t)(c0 + 32 * w + 16 + l2) * K + k0 + lk8, Bs + w * 1024 + 512);
    __syncthreads();

    half8 af[2], bf[4];
#pragma unroll
    for (int mr = 0; mr < 2; ++mr)
      af[mr] = *(const half8*)(As + (wr * 32 + mr * 16 + fr) * 32 + fg);
#pragma unroll
    for (int nr = 0; nr < 4; ++nr)
      bf[nr] = *(const half8*)(Bs + (wc * 64 + nr * 16 + fr) * 32 + fg);
#pragma unroll
    for (int mr = 0; mr < 2; ++mr)
#pragma unroll
      for (int nr = 0; nr < 4; ++nr)
        acc[mr][nr] = __builtin_amdgcn_mfma_f32_16x16x32_f16(af[mr], bf[nr], acc[mr][nr], 0, 0, 0);
    __syncthreads();
  }

  const int r0 = (lane >> 4) * 4;
#pragma unroll
  for (int nr = 0; nr < 4; ++nr) {
    int col = c0 + wc * 64 + nr * 16 + fr;
    float bv = bias ? bias[col] : 0.f;
    int h = col >> 6, o = col & 63;
#pragma unroll
    for (int mr = 0; mr < 2; ++mr) {
      f32x4 v = acc[mr][nr];
#pragma unroll
      for (int r = 0; r < 4; ++r) {
        int ra = ra0 + wr * 32 + mr * 16 + r0 + r;
        float val = v[r] + bv;
        if (PERM == 2) {
          int n = ra % NN, b = ra / NN;
          ((f16*)outp)[(((size_t)(b * 4 + h) * NN + n) << 6) + o] = (f16)val;
        } else if (OUTH) {
          ((f16*)outp)[(size_t)ra * ldo + col] = (f16)val;
        } else {
          ((float*)outp)[(size_t)ra * ldo + col] = val;
        }
      }
    }
  }
}

// ---------------- el/er, [n][16] layout (bh = b*4+h) ----------------
__global__ __launch_bounds__(256) void k_eler2h(
    const f16* __restrict__ xh, int lda,
    const float* __restrict__ alf, float* __restrict__ el2, float* __restrict__ er2)
{
  int wid = threadIdx.x >> 6, lane = threadIdx.x & 63;
  int ra = blockIdx.x * 4 + wid;        // b*NN+n
  int k0 = lane << 2;
  H4 hv;
  hv.u = *(const uint2*)(xh + (size_t)ra * lda + k0);
  float x0 = (float)hv.h[0], x1 = (float)hv.h[1], x2 = (float)hv.h[2], x3 = (float)hv.h[3];
  int n = ra % NN, b = ra / NN;
  int tb = (n << 4) + (b << 2);
#pragma unroll
  for (int oi = 0; oi < 8; ++oi) {
    float4 av = *(const float4*)(alf + (oi << 8) + k0);
    float s = x0 * av.x + x1 * av.y + x2 * av.z + x3 * av.w;
#pragma unroll
    for (int k = 32; k; k >>= 1) s += __shfl_xor(s, k);
    if (lane == 0) {
      if (oi < 4) el2[tb + oi] = s;
      else        er2[tb + (oi - 4)] = s;
    }
  }
}

// ---------------- softmax: one wave per node, all 16 bh in-lane ----------------
// lane = es*16 + bh (es = 4 edge slots). Reductions across es = 2-step shfl.
// Two exact passes (max, then exp+sum+write) — no atomics, no online rescale.
__global__ __launch_bounds__(256) void k_soft(
    const int* __restrict__ csr_src, const float* __restrict__ csr_w,
    const int* __restrict__ offs,
    const float* __restrict__ el2, const float* __restrict__ er2,
    float* __restrict__ ex_t, float* __restrict__ sbuf)
{
  const int t = threadIdx.x;
  const int w = t >> 6, lane = t & 63;
  const int n = blockIdx.x * 4 + w;
  const int bh = lane & 15, es = lane >> 4;
  const int s0 = offs[n], s1 = offs[n + 1];
  const float erv = er2[(n << 4) + bh];

  float m = -INFINITY;
  for (int e = s0 + es; e < s1; e += 4) {
    int src = csr_src[e];                       // broadcast within es-group
    float x = el2[(src << 4) + bh] + erv;       // 64B/row coalesced
    x = (x > 0.f) ? x : 0.1f * x;
    m = fmaxf(m, x * csr_w[e]);
  }
  m = fmaxf(m, __shfl_xor(m, 16));
  m = fmaxf(m, __shfl_xor(m, 32));

  float ps = 0.f;
  for (int e = s0 + es; e < s1; e += 4) {
    int src = csr_src[e];
    float x = el2[(src << 4) + bh] + erv;
    x = (x > 0.f) ? x : 0.1f * x;
    float a = __expf(x * csr_w[e] - m);
    ex_t[(size_t)bh * NE + e] = a;
    ps += a;
  }
  ps += __shfl_xor(ps, 16);
  ps += __shfl_xor(ps, 32);
  if (es == 0) sbuf[(size_t)bh * NN + n] = ps;
}

// ---------------- aggregate only: bh-split, wave-per-node ----------------
// blockIdx.x = chunk*16 + bh -> XCD = bid%8 = bh%8: per-XCD L2 keeps bh slices hot.
// lane = es*16+cg: es = edge slot (4-way edge ILP), cg = 4-channel group (uint2 loads).
__global__ __launch_bounds__(256) void k_edge5(
    const f16* __restrict__ featW_t, const float* __restrict__ ex_t, const float* __restrict__ sbuf,
    const int* __restrict__ csr_src, const int* __restrict__ offs,
    const float* __restrict__ b2, f16* __restrict__ outh)
{
  __shared__ float2 as_[4][64];        // {alpha, bitcast(src)} per wave
  const int t = threadIdx.x;
  const int w = t >> 6, lane = t & 63;
  const int bh = blockIdx.x & 15;
  const int n = (blockIdx.x >> 4) * 4 + w;
  const int s0 = offs[n], s1 = offs[n + 1];
  const f16* fW = featW_t + ((size_t)bh * NN << 6);
  const float* exs = ex_t + (size_t)bh * NE;
  const int es = lane >> 4;            // 0..3 edge slot
  const int cg = lane & 15;            // 0..15 channel group (4 ch)

  float a0 = 0.f, a1 = 0.f, a2 = 0.f, a3 = 0.f;

  for (int c0 = s0; c0 < s1; c0 += 64) {
    const int csz = min(64, s1 - c0);
    float alpha = 0.f;
    int src = 0;
    if (lane < csz) {                  // both loads coalesced (256B/wave)
      src = csr_src[c0 + lane];
      alpha = exs[c0 + lane];
    }
    as_[w][lane] = make_float2(alpha, __int_as_float(src));
    for (int e = 0; e < csz; e += 4) {
      float2 pp = as_[w][e + es];      // broadcast within each 16-lane group
      int sn = __float_as_int(pp.y);
      H4 fv;
      fv.u = *(const uint2*)(fW + ((size_t)sn << 6) + (cg << 2));
      float al = pp.x;
      a0 = fmaf(al, (float)fv.h[0], a0);
      a1 = fmaf(al, (float)fv.h[1], a1);
      a2 = fmaf(al, (float)fv.h[2], a2);
      a3 = fmaf(al, (float)fv.h[3], a3);
    }
  }
  // cross-edge-slot reduction (es bits = lane bits 4,5)
#pragma unroll
  for (int k = 16; k <= 32; k <<= 1) {
    a0 += __shfl_xor(a0, k);
    a1 += __shfl_xor(a1, k);
    a2 += __shfl_xor(a2, k);
    a3 += __shfl_xor(a3, k);
  }
  if (lane < 16) {
    float invs = (s1 > s0) ? 1.f / sbuf[(size_t)bh * NN + n] : 0.f;
    const float4 bv = *(const float4*)(b2 + (cg << 2));
    H4 o;
    o.h[0] = (f16)fmaxf(fmaf(a0, invs, bv.x), 0.f);
    o.h[1] = (f16)fmaxf(fmaf(a1, invs, bv.y), 0.f);
    o.h[2] = (f16)fmaxf(fmaf(a2, invs, bv.z), 0.f);
    o.h[3] = (f16)fmaxf(fmaf(a3, invs, bv.w), 0.f);
    const int b = bh >> 2, h = bh & 3;
    *(uint2*)(outh + (((size_t)b * NN + n) << 9) + (h << 6) + (cg << 2)) = o.u;
  }
}

// ---------------- launch ----------------
extern "C" void kernel_launch(void* const* d_in, const int* in_sizes, int n_in,
                              void* d_out, int out_size, void* d_ws, size_t ws_size,
                              hipStream_t stream) {
  const float* sol    = (const float*)d_in[0];
  const float* w      = (const float*)d_in[1];
  const float* fc_w   = (const float*)d_in[2];
  const float* attn_l = (const float*)d_in[3];
  const float* attn_r = (const float*)d_in[4];
  const float* ofc_w  = (const float*)d_in[5];
  const float* ofc_b  = (const float*)d_in[6];
  const float* mlp_w  = (const float*)d_in[7];
  const float* mlp_b  = (const float*)d_in[8];
  const int*   d_src  = (const int*)d_in[9];
  const int*   d_dst  = (const int*)d_in[10];
  float* out = (float*)d_out;

  char* p = (char*)d_ws;
  auto alloc = [&](size_t bytes) { char* r = p; p += (bytes + 255) & ~(size_t)255; return r; };
  f16*   solh    = (f16*)alloc((size_t)NM * 256 * 2);
  f16*   out01h  = (f16*)alloc((size_t)NM * 512 * 2);
  f16*   featWt  = (f16*)alloc((size_t)NT * 64 * 2);       // [16][NN][64]
  f16*   fwh     = (f16*)alloc((size_t)ND * ND * 2);
  f16*   mlph    = (f16*)alloc((size_t)ND * 512 * 2);
  float* el2     = (float*)alloc((size_t)NT * 4);          // [NN][16]
  float* er2     = (float*)alloc((size_t)NT * 4);
  float* alf     = (float*)alloc((size_t)8 * ND * 4);
  float* ex_t    = (float*)alloc((size_t)16 * NE * 4);     // [16][NE] 10.24MB
  float* sbuf    = (float*)alloc((size_t)NT * 4);          // [16][NN]
  int*   deg     = (int*)alloc((size_t)(NN + 1) * 4);
  int*   offs    = (int*)alloc((size_t)(NN + 1) * 4);
  int*   cursor  = (int*)alloc((size_t)NN * 4);
  int*   csr_src = (int*)alloc((size_t)NE * 4);
  float* csr_w   = (float*)alloc((size_t)NE * 4);
  if ((size_t)(p - (char*)d_ws) > ws_size) return;

  hipMemsetAsync(deg, 0, (size_t)NN * 4, stream);
  hipMemsetAsync(cursor, 0, (size_t)NN * 4, stream);
  k_deg<<<NE / 256, 256, 0, stream>>>(d_dst, deg);
  k_scan<<<1, 1024, 0, stream>>>(deg, offs);
  k_scatter<<<NE / 256, 256, 0, stream>>>(d_src, d_dst, w, offs, cursor, csr_src, csr_w);

  k_cvt_sol<<<NM * 64 / 256, 256, 0, stream>>>(sol, solh);
  k_cvt4<<<(ND * 512 / 4 + 255) / 256, 256, 0, stream>>>(mlp_w, mlph, ND * 512 / 4);

  for (int l = 0; l < 2; ++l) {
    const float* fcl = fc_w + (size_t)l * ND * ND;
    k_fuse_wh<<<256, 256, 0, stream>>>(fcl, ofc_w + (size_t)l * 64 * 64, fwh);
    k_fuse_attn<<<8, 256, 0, stream>>>(fcl, attn_l + (size_t)l * NH * 64, attn_r + (size_t)l * NH * 64, alf);
    const f16* Ah = (l == 0) ? solh : out01h;
    int lda = (l == 0) ? 256 : 512;
    k_gemm_f16<2, 1><<<dim3(NM / 64, ND / 128), 256, 0, stream>>>(
        Ah, lda, 256, fwh, nullptr, featWt, 64);
    k_eler2h<<<NM / 4, 256, 0, stream>>>(Ah, lda, alf, el2, er2);
    k_soft<<<NN / 4, 256, 0, stream>>>(csr_src, csr_w, offs, el2, er2, ex_t, sbuf);
    k_edge5<<<(NN / 4) * 16, 256, 0, stream>>>(featWt, ex_t, sbuf, csr_src, offs,
                                               ofc_b + (size_t)l * 64, out01h + (l == 0 ? 0 : 256));
  }

  k_gemm_f16<0, 0><<<dim3(NM / 64, ND / 128), 256, 0, stream>>>(
      out01h, 512, 512, mlph, mlp_b, out, 256);
}

// Round 8
// 270.194 us; speedup vs baseline: 3.1480x; 1.2630x over previous
//
#include <hip/hip_runtime.h>
#include <math.h>

#define NN 10000
#define NE 160000
#define NB 4
#define NH 4
#define ND 256
#define NT (NN * 16)        // (n,b,h) triples
#define NM 40000            // GEMM rows (b*NN+n)

typedef _Float16 f16;
typedef _Float16 half8 __attribute__((ext_vector_type(8)));
typedef _Float16 h2 __attribute__((ext_vector_type(2)));
typedef float f32x4 __attribute__((ext_vector_type(4)));

union H4 { uint2 u; f16 h[4]; };
union U2H { unsigned u; h2 h; };

__device__ __forceinline__ void gload_lds16(const void* g, void* l) {
  __builtin_amdgcn_global_load_lds((const __attribute__((address_space(1))) void*)g,
                                   (__attribute__((address_space(3))) void*)l, 16, 0, 0);
}

// ---------------- CSR build ----------------
__global__ __launch_bounds__(256) void k_deg(const int* __restrict__ dst, int* __restrict__ deg) {
  int e = blockIdx.x * 256 + threadIdx.x;
  if (e < NE) atomicAdd(&deg[dst[e]], 1);
}

__global__ __launch_bounds__(1024) void k_scan(const int* __restrict__ deg, int* __restrict__ offs) {
  __shared__ int tmp[1024];
  __shared__ int carry_s;
  if (threadIdx.x == 0) carry_s = 0;
  __syncthreads();
  for (int base = 0; base < NN; base += 1024) {
    int i = base + (int)threadIdx.x;
    int v = (i < NN) ? deg[i] : 0;
    int c0 = carry_s;
    tmp[threadIdx.x] = v;
    __syncthreads();
    for (int s = 1; s < 1024; s <<= 1) {
      int add = (threadIdx.x >= (unsigned)s) ? tmp[threadIdx.x - s] : 0;
      __syncthreads();
      tmp[threadIdx.x] += add;
      __syncthreads();
    }
    if (i < NN) offs[i] = c0 + tmp[threadIdx.x] - v;   // exclusive
    int tot = tmp[1023];
    __syncthreads();
    if (threadIdx.x == 0) carry_s = c0 + tot;
    __syncthreads();
  }
  if (threadIdx.x == 0) offs[NN] = carry_s;
}

__global__ __launch_bounds__(256) void k_scatter(const int* __restrict__ src, const int* __restrict__ dst,
                                                 const float* __restrict__ w, const int* __restrict__ offs,
                                                 int* __restrict__ cursor, int* __restrict__ csr_src,
                                                 float* __restrict__ csr_w) {
  int e = blockIdx.x * 256 + threadIdx.x;
  if (e < NE) {
    int d = dst[e];
    int slot = offs[d] + atomicAdd(&cursor[d], 1);
    csr_src[slot] = src[e];
    csr_w[slot] = w[e];
  }
}

// ---------------- converters ----------------
__global__ __launch_bounds__(256) void k_cvt_sol(const float* __restrict__ sol, f16* __restrict__ solh) {
  int i = blockIdx.x * 256 + threadIdx.x;
  int row = i >> 6, q = i & 63;
  int k = q << 2;
  const float* s = (k < 128) ? (sol + (size_t)row * 128 + k)
                             : (sol + (size_t)(NM + row) * 128 + (k - 128));
  float4 v = *(const float4*)s;
  H4 h;
  h.h[0] = (f16)v.x; h.h[1] = (f16)v.y; h.h[2] = (f16)v.z; h.h[3] = (f16)v.w;
  *(uint2*)(solh + (size_t)row * 256 + k) = h.u;
}

__global__ __launch_bounds__(256) void k_cvt4(const float* __restrict__ in, f16* __restrict__ out, int n4) {
  int i = blockIdx.x * 256 + threadIdx.x;
  if (i < n4) {
    float4 v = *(const float4*)(in + (size_t)i * 4);
    H4 h;
    h.h[0] = (f16)v.x; h.h[1] = (f16)v.y; h.h[2] = (f16)v.z; h.h[3] = (f16)v.w;
    *(uint2*)(out + (size_t)i * 4) = h.u;
  }
}

// ---------------- weight fusion ----------------
__global__ __launch_bounds__(256) void k_fuse_wh(const float* __restrict__ fc_w, const float* __restrict__ ofc_w,
                                                 f16* __restrict__ fwh) {
  int r = blockIdx.x;        // 0..255 = h*64+o
  int d = threadIdx.x;       // 0..255
  int h = r >> 6, o = r & 63;
  float acc = 0.f;
  for (int f = 0; f < 64; ++f)
    acc = fmaf(ofc_w[(o << 6) + f], fc_w[(((h << 6) + f) << 8) + d], acc);
  fwh[(r << 8) + d] = (f16)acc;
}

__global__ __launch_bounds__(256) void k_fuse_attn(const float* __restrict__ fc_w,
                                                   const float* __restrict__ al, const float* __restrict__ ar,
                                                   float* __restrict__ alf) {
  int r = blockIdx.x;        // 0..7
  int d = threadIdx.x;
  int h = r & 3;
  const float* a = (r < 4) ? al : ar;
  float acc = 0.f;
  for (int f = 0; f < 64; ++f)
    acc = fmaf(a[(h << 6) + f], fc_w[(((h << 6) + f) << 8) + d], acc);
  alf[(r << 8) + d] = acc;
}

// ---------------- MFMA fp16 GEMM ----------------
// out[ra][col] (row-major, ldo), fp16 or fp32 per OUTH, optional bias.
template<int OUTH>
__global__ __launch_bounds__(256) void k_gemm_f16(
    const f16* __restrict__ A, int lda, int K,
    const f16* __restrict__ W,
    const float* __restrict__ bias,
    void* __restrict__ outp, int ldo)
{
  __shared__ __align__(16) f16 As[64 * 32];
  __shared__ __align__(16) f16 Bs[128 * 32];
  const int tid = threadIdx.x;
  const int lane = tid & 63;
  const int w = tid >> 6;
  const int wr = w >> 1, wc = w & 1;
  const int ra0 = blockIdx.x * 64;
  const int c0 = blockIdx.y * 128;
  const int l2 = lane >> 2;
  const int lk8 = (lane & 3) * 8;

  f32x4 acc[2][4];
#pragma unroll
  for (int mr = 0; mr < 2; ++mr)
#pragma unroll
    for (int nr = 0; nr < 4; ++nr) acc[mr][nr] = (f32x4)0.f;

  const int fr = lane & 15;
  const int fg = (lane >> 4) * 8;

  for (int k0 = 0; k0 < K; k0 += 32) {
    gload_lds16(A + (size_t)(ra0 + 16 * w + l2) * lda + k0 + lk8, As + w * 512);
    gload_lds16(W + (size_t)(c0 + 32 * w + l2) * K + k0 + lk8, Bs + w * 1024);
    gload_lds16(W + (size_t)(c0 + 32 * w + 16 + l2) * K + k0 + lk8, Bs + w * 1024 + 512);
    __syncthreads();

    half8 af[2], bf[4];
#pragma unroll
    for (int mr = 0; mr < 2; ++mr)
      af[mr] = *(const half8*)(As + (wr * 32 + mr * 16 + fr) * 32 + fg);
#pragma unroll
    for (int nr = 0; nr < 4; ++nr)
      bf[nr] = *(const half8*)(Bs + (wc * 64 + nr * 16 + fr) * 32 + fg);
#pragma unroll
    for (int mr = 0; mr < 2; ++mr)
#pragma unroll
      for (int nr = 0; nr < 4; ++nr)
        acc[mr][nr] = __builtin_amdgcn_mfma_f32_16x16x32_f16(af[mr], bf[nr], acc[mr][nr], 0, 0, 0);
    __syncthreads();
  }

  const int r0 = (lane >> 4) * 4;
#pragma unroll
  for (int nr = 0; nr < 4; ++nr) {
    int col = c0 + wc * 64 + nr * 16 + fr;
    float bv = bias ? bias[col] : 0.f;
#pragma unroll
    for (int mr = 0; mr < 2; ++mr) {
      f32x4 v = acc[mr][nr];
#pragma unroll
      for (int r = 0; r < 4; ++r) {
        int ra = ra0 + wr * 32 + mr * 16 + r0 + r;
        float val = v[r] + bv;
        if (OUTH) ((f16*)outp)[(size_t)ra * ldo + col] = (f16)val;
        else      ((float*)outp)[(size_t)ra * ldo + col] = val;
      }
    }
  }
}

// ---------------- el/er, [n][16] layout (bh = b*4+h) ----------------
__global__ __launch_bounds__(256) void k_eler2h(
    const f16* __restrict__ xh, int lda,
    const float* __restrict__ alf, float* __restrict__ el2, float* __restrict__ er2)
{
  int wid = threadIdx.x >> 6, lane = threadIdx.x & 63;
  int ra = blockIdx.x * 4 + wid;        // b*NN+n
  int k0 = lane << 2;
  H4 hv;
  hv.u = *(const uint2*)(xh + (size_t)ra * lda + k0);
  float x0 = (float)hv.h[0], x1 = (float)hv.h[1], x2 = (float)hv.h[2], x3 = (float)hv.h[3];
  int n = ra % NN, b = ra / NN;
  int tb = (n << 4) + (b << 2);
#pragma unroll
  for (int oi = 0; oi < 8; ++oi) {
    float4 av = *(const float4*)(alf + (oi << 8) + k0);
    float s = x0 * av.x + x1 * av.y + x2 * av.z + x3 * av.w;
#pragma unroll
    for (int k = 32; k; k >>= 1) s += __shfl_xor(s, k);
    if (lane == 0) {
      if (oi < 4) el2[tb + oi] = s;
      else        er2[tb + (oi - 4)] = s;
    }
  }
}

// ---------------- softmax: one wave per node, all 16 bh in-lane ----------------
// lane = es*16 + bh. Writes alpha as SPLATTED f16x2 pairs exsp[b][e][4h] and
// reciprocal sums sinv[b][n][4h] so the aggregate kernel does zero softmax work.
__global__ __launch_bounds__(256) void k_soft(
    const int* __restrict__ csr_src, const float* __restrict__ csr_w,
    const int* __restrict__ offs,
    const float* __restrict__ el2, const float* __restrict__ er2,
    unsigned* __restrict__ exsp, float* __restrict__ sinv)
{
  const int t = threadIdx.x;
  const int w = t >> 6, lane = t & 63;
  const int n = blockIdx.x * 4 + w;
  const int bh = lane & 15, es = lane >> 4;
  const int b = bh >> 2, h = bh & 3;
  const int s0 = offs[n], s1 = offs[n + 1];
  const float erv = er2[(n << 4) + bh];

  float m = -INFINITY;
  for (int e = s0 + es; e < s1; e += 4) {
    int src = csr_src[e];
    float x = el2[(src << 4) + bh] + erv;
    x = (x > 0.f) ? x : 0.1f * x;
    m = fmaxf(m, x * csr_w[e]);
  }
  m = fmaxf(m, __shfl_xor(m, 16));
  m = fmaxf(m, __shfl_xor(m, 32));

  float ps = 0.f;
  for (int e = s0 + es; e < s1; e += 4) {
    int src = csr_src[e];
    float x = el2[(src << 4) + bh] + erv;
    x = (x > 0.f) ? x : 0.1f * x;
    float a = __expf(x * csr_w[e] - m);
    f16 ah = (f16)a;
    U2H sp; sp.h[0] = ah; sp.h[1] = ah;
    exsp[(((size_t)b * NE + e) << 2) + h] = sp.u;
    ps += a;
  }
  ps += __shfl_xor(ps, 16);
  ps += __shfl_xor(ps, 32);
  if (es == 0) sinv[(((size_t)b * NN + n) << 2) + h] = (s1 > s0) ? 1.f / ps : 0.f;
}

// ---------------- aggregate: wave per (n,b), all 4 heads = 256 ch ----------------
// blockIdx.x = chunk*4 + b -> XCD = bid%8 serves b = xcd&3 (featW b-slice 5.1MB).
// lane owns channels lane*4..+3 (head = lane>>4); per edge: 2 ds_read broadcast +
// 1 dwordx2 gather (512B/wave) + 2 v_pk_fma_f16. No cross-lane reduction.
__global__ __launch_bounds__(256) void k_edge6(
    const f16* __restrict__ featW_b, const unsigned* __restrict__ exsp,
    const float* __restrict__ sinv, const int* __restrict__ csr_src,
    const int* __restrict__ offs, const float* __restrict__ b2, f16* __restrict__ outh)
{
  __shared__ __align__(16) unsigned aalp[4][64][4];  // [wave][edge][head] splat pairs
  __shared__ unsigned asrc[4][64];
  const int t = threadIdx.x;
  const int w = t >> 6, lane = t & 63;
  const int b = blockIdx.x & 3;
  const int n = (blockIdx.x >> 2) * 4 + w;
  const int s0 = offs[n], s1 = offs[n + 1];
  const int hidx = lane >> 4;
  const f16* fW = featW_b + ((size_t)b * NN << 8);
  const unsigned* exb = exsp + ((size_t)b * NE << 2);

  h2 acc0 = {(f16)0.f, (f16)0.f};
  h2 acc1 = {(f16)0.f, (f16)0.f};

  for (int c0 = s0; c0 < s1; c0 += 64) {
    const int csz = min(64, s1 - c0);
    if (lane < csz) {
      asrc[w][lane] = (unsigned)csr_src[c0 + lane];
      *(uint4*)(&aalp[w][lane][0]) = *(const uint4*)(exb + ((size_t)(c0 + lane) << 2));
    }
    for (int e = 0; e < csz; ++e) {
      unsigned su = asrc[w][e];                    // broadcast
      U2H al; al.u = aalp[w][e][hidx];             // 4-way broadcast, bank-clean
      const uint2 fv = *(const uint2*)(fW + ((size_t)su << 8) + (lane << 2));
      U2H f0, f1; f0.u = fv.x; f1.u = fv.y;
      acc0 += f0.h * al.h;
      acc1 += f1.h * al.h;
    }
  }

  const float invv = sinv[(((size_t)b * NN + n) << 2) + hidx];
  const float4 bv = *(const float4*)(b2 + ((lane & 15) << 2));
  H4 o;
  o.h[0] = (f16)fmaxf(fmaf((float)acc0[0], invv, bv.x), 0.f);
  o.h[1] = (f16)fmaxf(fmaf((float)acc0[1], invv, bv.y), 0.f);
  o.h[2] = (f16)fmaxf(fmaf((float)acc1[0], invv, bv.z), 0.f);
  o.h[3] = (f16)fmaxf(fmaf((float)acc1[1], invv, bv.w), 0.f);
  *(uint2*)(outh + ((size_t)(b * NN + n) << 9) + (lane << 2)) = o.u;
}

// ---------------- launch ----------------
extern "C" void kernel_launch(void* const* d_in, const int* in_sizes, int n_in,
                              void* d_out, int out_size, void* d_ws, size_t ws_size,
                              hipStream_t stream) {
  const float* sol    = (const float*)d_in[0];
  const float* w      = (const float*)d_in[1];
  const float* fc_w   = (const float*)d_in[2];
  const float* attn_l = (const float*)d_in[3];
  const float* attn_r = (const float*)d_in[4];
  const float* ofc_w  = (const float*)d_in[5];
  const float* ofc_b  = (const float*)d_in[6];
  const float* mlp_w  = (const float*)d_in[7];
  const float* mlp_b  = (const float*)d_in[8];
  const int*   d_src  = (const int*)d_in[9];
  const int*   d_dst  = (const int*)d_in[10];
  float* out = (float*)d_out;

  char* p = (char*)d_ws;
  auto alloc = [&](size_t bytes) { char* r = p; p += (bytes + 255) & ~(size_t)255; return r; };
  f16*   solh    = (f16*)alloc((size_t)NM * 256 * 2);
  f16*   out01h  = (f16*)alloc((size_t)NM * 512 * 2);
  f16*   featWb  = (f16*)alloc((size_t)NM * 256 * 2);      // [b*NN+n][256] row-major
  f16*   fwh     = (f16*)alloc((size_t)ND * ND * 2);
  f16*   mlph    = (f16*)alloc((size_t)ND * 512 * 2);
  float* el2     = (float*)alloc((size_t)NT * 4);          // [NN][16]
  float* er2     = (float*)alloc((size_t)NT * 4);
  float* alf     = (float*)alloc((size_t)8 * ND * 4);
  unsigned* exsp = (unsigned*)alloc((size_t)4 * NE * 4 * 4); // [4][NE][4] splat pairs 10.24MB
  float* sinv    = (float*)alloc((size_t)NT * 4);          // [4][NN][4]
  int*   deg     = (int*)alloc((size_t)(NN + 1) * 4);
  int*   offs    = (int*)alloc((size_t)(NN + 1) * 4);
  int*   cursor  = (int*)alloc((size_t)NN * 4);
  int*   csr_src = (int*)alloc((size_t)NE * 4);
  float* csr_w   = (float*)alloc((size_t)NE * 4);
  if ((size_t)(p - (char*)d_ws) > ws_size) return;

  hipMemsetAsync(deg, 0, (size_t)NN * 4, stream);
  hipMemsetAsync(cursor, 0, (size_t)NN * 4, stream);
  k_deg<<<NE / 256, 256, 0, stream>>>(d_dst, deg);
  k_scan<<<1, 1024, 0, stream>>>(deg, offs);
  k_scatter<<<NE / 256, 256, 0, stream>>>(d_src, d_dst, w, offs, cursor, csr_src, csr_w);

  k_cvt_sol<<<NM * 64 / 256, 256, 0, stream>>>(sol, solh);
  k_cvt4<<<(ND * 512 / 4 + 255) / 256, 256, 0, stream>>>(mlp_w, mlph, ND * 512 / 4);

  for (int l = 0; l < 2; ++l) {
    const float* fcl = fc_w + (size_t)l * ND * ND;
    k_fuse_wh<<<256, 256, 0, stream>>>(fcl, ofc_w + (size_t)l * 64 * 64, fwh);
    k_fuse_attn<<<8, 256, 0, stream>>>(fcl, attn_l + (size_t)l * NH * 64, attn_r + (size_t)l * NH * 64, alf);
    const f16* Ah = (l == 0) ? solh : out01h;
    int lda = (l == 0) ? 256 : 512;
    k_gemm_f16<1><<<dim3(NM / 64, ND / 128), 256, 0, stream>>>(
        Ah, lda, 256, fwh, nullptr, featWb, 256);
    k_eler2h<<<NM / 4, 256, 0, stream>>>(Ah, lda, alf, el2, er2);
    k_soft<<<NN / 4, 256, 0, stream>>>(csr_src, csr_w, offs, el2, er2, exsp, sinv);
    k_edge6<<<(NN / 4) * 4, 256, 0, stream>>>(featWb, exsp, sinv, csr_src, offs,
                                              ofc_b + (size_t)l * 64, out01h + (l == 0 ? 0 : 256));
  }

  k_gemm_f16<0><<<dim3(NM / 64, ND / 128), 256, 0, stream>>>(
      out01h, 512, 512, mlph, mlp_b, out, 256);
}

// Round 9
// 205.399 us; speedup vs baseline: 4.1410x; 1.3155x over previous
//
#include <hip/hip_runtime.h>
#include <math.h>

#define NN 10000
#define NE 160000
#define NB 4
#define NH 4
#define ND 256
#define NT (NN * 16)        // (n,b,h) triples
#define NM 40000            // GEMM rows (b*NN+n)

typedef _Float16 f16;
typedef _Float16 half8 __attribute__((ext_vector_type(8)));
typedef _Float16 h2 __attribute__((ext_vector_type(2)));
typedef float f32x4 __attribute__((ext_vector_type(4)));

union H4 { uint2 u; f16 h[4]; };
union U2H { unsigned u; h2 h; };

__device__ __forceinline__ void gload_lds16(const void* g, void* l) {
  __builtin_amdgcn_global_load_lds((const __attribute__((address_space(1))) void*)g,
                                   (__attribute__((address_space(3))) void*)l, 16, 0, 0);
}

// ---------------- CSR build ----------------
__global__ __launch_bounds__(256) void k_deg(const int* __restrict__ dst, int* __restrict__ deg) {
  int e = blockIdx.x * 256 + threadIdx.x;
  if (e < NE) atomicAdd(&deg[dst[e]], 1);
}

// 3-barrier scan: 10 elems/thread serial + wave shfl scan + cross-wave combine
__global__ __launch_bounds__(1024) void k_scan2(const int* __restrict__ deg, int* __restrict__ offs) {
  __shared__ int wsum[16];
  __shared__ int wbase[17];
  const int t = threadIdx.x, lane = t & 63, wv = t >> 6;
  int v[10];
  int s = 0;
  if (t < 1000) {
#pragma unroll
    for (int i = 0; i < 10; ++i) { v[i] = deg[t * 10 + i]; s += v[i]; }
  }
  int inc = s;
#pragma unroll
  for (int k = 1; k < 64; k <<= 1) {
    int u = __shfl_up(inc, k);
    if (lane >= k) inc += u;
  }
  if (lane == 63) wsum[wv] = inc;
  __syncthreads();
  if (t == 0) {
    int c = 0;
#pragma unroll
    for (int i = 0; i < 16; ++i) { wbase[i] = c; c += wsum[i]; }
    wbase[16] = c;
    offs[NN] = c;
  }
  __syncthreads();
  if (t < 1000) {
    int c = wbase[wv] + inc - s;   // exclusive base for this thread
#pragma unroll
    for (int i = 0; i < 10; ++i) { offs[t * 10 + i] = c; c += v[i]; }
  }
}

__global__ __launch_bounds__(256) void k_scatter(const int* __restrict__ src, const int* __restrict__ dst,
                                                 const float* __restrict__ w, const int* __restrict__ offs,
                                                 int* __restrict__ cursor, int* __restrict__ csr_src,
                                                 float* __restrict__ csr_w) {
  int e = blockIdx.x * 256 + threadIdx.x;
  if (e < NE) {
    int d = dst[e];
    int slot = offs[d] + atomicAdd(&cursor[d], 1);
    csr_src[slot] = src[e];
    csr_w[slot] = w[e];
  }
}

// ---------------- converters ----------------
__global__ __launch_bounds__(256) void k_cvt4(const float* __restrict__ in, f16* __restrict__ out, int n4) {
  int i = blockIdx.x * 256 + threadIdx.x;
  if (i < n4) {
    float4 v = *(const float4*)(in + (size_t)i * 4);
    H4 h;
    h.h[0] = (f16)v.x; h.h[1] = (f16)v.y; h.h[2] = (f16)v.z; h.h[3] = (f16)v.w;
    *(uint2*)(out + (size_t)i * 4) = h.u;
  }
}

// ---------------- weight fusion (fwh + alfh in one launch) ----------------
// r<256: fwh[h*64+o, d] = sum_f ofc_w[o,f]*fc_w[h*64+f, d]
// r>=256: rr=r-256: rr<8 -> alfh[rr,d] = (al|ar fused); rr in 8..15 -> 0
__global__ __launch_bounds__(256) void k_fuse(const float* __restrict__ fc_w, const float* __restrict__ ofc_w,
                                              const float* __restrict__ al, const float* __restrict__ ar,
                                              f16* __restrict__ fwh, f16* __restrict__ alfh) {
  int r = blockIdx.x;
  int d = threadIdx.x;
  if (r < 256) {
    int h = r >> 6, o = r & 63;
    float acc = 0.f;
    for (int f = 0; f < 64; ++f)
      acc = fmaf(ofc_w[(o << 6) + f], fc_w[(((h << 6) + f) << 8) + d], acc);
    fwh[(r << 8) + d] = (f16)acc;
  } else {
    int rr = r - 256;
    float acc = 0.f;
    if (rr < 8) {
      int h = rr & 3;
      const float* a = (rr < 4) ? al : ar;
      for (int f = 0; f < 64; ++f)
        acc = fmaf(a[(h << 6) + f], fc_w[(((h << 6) + f) << 8) + d], acc);
    }
    alfh[(rr << 8) + d] = (f16)acc;
  }
}

// ---------------- MFMA fp16 GEMM (+optional el/er fusion, +optional fp32 cvt) ----------------
// out[ra][col] row-major. CVT=1: A = sol fp32 [2][NM][128] (concat K=256).
// EL=1: also el2/er2 via 8 extra cols (alfh [16][256], rows 8-15 zero), y==0 wc==0 waves.
template<int OUTH, int EL, int CVT>
__global__ __launch_bounds__(256) void k_gemm_f16(
    const void* __restrict__ A, int lda, int K,
    const f16* __restrict__ W,
    const float* __restrict__ bias,
    void* __restrict__ outp, int ldo,
    const f16* __restrict__ alfh, float* __restrict__ el2, float* __restrict__ er2)
{
  __shared__ __align__(16) f16 As[64 * 32];
  __shared__ __align__(16) f16 Bs[128 * 32];
  const int tid = threadIdx.x;
  const int lane = tid & 63;
  const int w = tid >> 6;
  const int wr = w >> 1, wc = w & 1;
  const int ra0 = blockIdx.x * 64;
  const int c0 = blockIdx.y * 128;
  const int l2 = lane >> 2;
  const int lk8 = (lane & 3) * 8;

  f32x4 acc[2][4];
#pragma unroll
  for (int mr = 0; mr < 2; ++mr)
#pragma unroll
    for (int nr = 0; nr < 4; ++nr) acc[mr][nr] = (f32x4)0.f;
  f32x4 accel[2];
  accel[0] = (f32x4)0.f; accel[1] = (f32x4)0.f;
  const bool doEl = EL && (blockIdx.y == 0) && (wc == 0);

  const int fr = lane & 15;
  const int fg = (lane >> 4) * 8;

  for (int k0 = 0; k0 < K; k0 += 32) {
    if (CVT) {
      // reg-staged fp32 -> fp16 (same lane-linear layout as global_load_lds)
      const float* sf = (const float*)A;
      int ra = ra0 + 16 * w + l2;
      int kk = k0 + lk8;
      const float* ps = (kk < 128) ? sf + (size_t)ra * 128 + kk
                                   : sf + (size_t)(NM + ra) * 128 + (kk - 128);
      float4 p0 = *(const float4*)ps;
      float4 p1 = *(const float4*)(ps + 4);
      half8 hv;
      hv[0] = (f16)p0.x; hv[1] = (f16)p0.y; hv[2] = (f16)p0.z; hv[3] = (f16)p0.w;
      hv[4] = (f16)p1.x; hv[5] = (f16)p1.y; hv[6] = (f16)p1.z; hv[7] = (f16)p1.w;
      *(half8*)(As + w * 512 + (lane << 3)) = hv;
    } else {
      gload_lds16((const f16*)A + (size_t)(ra0 + 16 * w + l2) * lda + k0 + lk8, As + w * 512);
    }
    gload_lds16(W + (size_t)(c0 + 32 * w + l2) * K + k0 + lk8, Bs + w * 1024);
    gload_lds16(W + (size_t)(c0 + 32 * w + 16 + l2) * K + k0 + lk8, Bs + w * 1024 + 512);
    __syncthreads();

    half8 af[2], bf[4];
#pragma unroll
    for (int mr = 0; mr < 2; ++mr)
      af[mr] = *(const half8*)(As + (wr * 32 + mr * 16 + fr) * 32 + fg);
#pragma unroll
    for (int nr = 0; nr < 4; ++nr)
      bf[nr] = *(const half8*)(Bs + (wc * 64 + nr * 16 + fr) * 32 + fg);
#pragma unroll
    for (int mr = 0; mr < 2; ++mr)
#pragma unroll
      for (int nr = 0; nr < 4; ++nr)
        acc[mr][nr] = __builtin_amdgcn_mfma_f32_16x16x32_f16(af[mr], bf[nr], acc[mr][nr], 0, 0, 0);
    if (doEl) {
      half8 bal = *(const half8*)(alfh + fr * 256 + k0 + fg);   // L1-hot 8KB
#pragma unroll
      for (int mr = 0; mr < 2; ++mr)
        accel[mr] = __builtin_amdgcn_mfma_f32_16x16x32_f16(af[mr], bal, accel[mr], 0, 0, 0);
    }
    __syncthreads();
  }

  const int r0 = (lane >> 4) * 4;
#pragma unroll
  for (int nr = 0; nr < 4; ++nr) {
    int col = c0 + wc * 64 + nr * 16 + fr;
    float bv = bias ? bias[col] : 0.f;
#pragma unroll
    for (int mr = 0; mr < 2; ++mr) {
      f32x4 v = acc[mr][nr];
#pragma unroll
      for (int r = 0; r < 4; ++r) {
        int ra = ra0 + wr * 32 + mr * 16 + r0 + r;
        float val = v[r] + bv;
        if (OUTH) ((f16*)outp)[(size_t)ra * ldo + col] = (f16)val;
        else      ((float*)outp)[(size_t)ra * ldo + col] = val;
      }
    }
  }
  if (doEl && fr < 8) {
#pragma unroll
    for (int mr = 0; mr < 2; ++mr) {
#pragma unroll
      for (int r = 0; r < 4; ++r) {
        int ra = ra0 + wr * 32 + mr * 16 + r0 + r;
        int n = ra % NN, b = ra / NN;
        int tb = (n << 4) + (b << 2);
        float val = accel[mr][r];
        if (fr < 4) el2[tb + fr] = val;
        else        er2[tb + (fr - 4)] = val;
      }
    }
  }
}

// ---------------- softmax: one wave per node, all 16 bh in-lane ----------------
// lane = es*16 + bh. Writes alpha as SPLATTED f16x2 pairs exsp[b][e][4h] and
// reciprocal sums sinv[b][n][4h] so the aggregate kernel does zero softmax work.
__global__ __launch_bounds__(256) void k_soft(
    const int* __restrict__ csr_src, const float* __restrict__ csr_w,
    const int* __restrict__ offs,
    const float* __restrict__ el2, const float* __restrict__ er2,
    unsigned* __restrict__ exsp, float* __restrict__ sinv)
{
  const int t = threadIdx.x;
  const int w = t >> 6, lane = t & 63;
  const int n = blockIdx.x * 4 + w;
  const int bh = lane & 15, es = lane >> 4;
  const int b = bh >> 2, h = bh & 3;
  const int s0 = offs[n], s1 = offs[n + 1];
  const float erv = er2[(n << 4) + bh];

  float m = -INFINITY;
  for (int e = s0 + es; e < s1; e += 4) {
    int src = csr_src[e];
    float x = el2[(src << 4) + bh] + erv;
    x = (x > 0.f) ? x : 0.1f * x;
    m = fmaxf(m, x * csr_w[e]);
  }
  m = fmaxf(m, __shfl_xor(m, 16));
  m = fmaxf(m, __shfl_xor(m, 32));

  float ps = 0.f;
  for (int e = s0 + es; e < s1; e += 4) {
    int src = csr_src[e];
    float x = el2[(src << 4) + bh] + erv;
    x = (x > 0.f) ? x : 0.1f * x;
    float a = __expf(x * csr_w[e] - m);
    f16 ah = (f16)a;
    U2H sp; sp.h[0] = ah; sp.h[1] = ah;
    exsp[(((size_t)b * NE + e) << 2) + h] = sp.u;
    ps += a;
  }
  ps += __shfl_xor(ps, 16);
  ps += __shfl_xor(ps, 32);
  if (es == 0) sinv[(((size_t)b * NN + n) << 2) + h] = (s1 > s0) ? 1.f / ps : 0.f;
}

// ---------------- aggregate: wave per (n,b), all 4 heads = 256 ch ----------------
__global__ __launch_bounds__(256) void k_edge6(
    const f16* __restrict__ featW_b, const unsigned* __restrict__ exsp,
    const float* __restrict__ sinv, const int* __restrict__ csr_src,
    const int* __restrict__ offs, const float* __restrict__ b2, f16* __restrict__ outh)
{
  __shared__ __align__(16) unsigned aalp[4][64][4];  // [wave][edge][head] splat pairs
  __shared__ unsigned asrc[4][64];
  const int t = threadIdx.x;
  const int w = t >> 6, lane = t & 63;
  const int b = blockIdx.x & 3;
  const int n = (blockIdx.x >> 2) * 4 + w;
  const int s0 = offs[n], s1 = offs[n + 1];
  const int hidx = lane >> 4;
  const f16* fW = featW_b + ((size_t)b * NN << 8);
  const unsigned* exb = exsp + ((size_t)b * NE << 2);

  h2 acc0 = {(f16)0.f, (f16)0.f};
  h2 acc1 = {(f16)0.f, (f16)0.f};

  for (int c0 = s0; c0 < s1; c0 += 64) {
    const int csz = min(64, s1 - c0);
    if (lane < csz) {
      asrc[w][lane] = (unsigned)csr_src[c0 + lane];
      *(uint4*)(&aalp[w][lane][0]) = *(const uint4*)(exb + ((size_t)(c0 + lane) << 2));
    }
#pragma unroll 2
    for (int e = 0; e < csz; ++e) {
      unsigned su = asrc[w][e];                    // broadcast
      U2H al; al.u = aalp[w][e][hidx];             // 4-way broadcast, bank-clean
      const uint2 fv = *(const uint2*)(fW + ((size_t)su << 8) + (lane << 2));
      U2H f0, f1; f0.u = fv.x; f1.u = fv.y;
      acc0 += f0.h * al.h;
      acc1 += f1.h * al.h;
    }
  }

  const float invv = sinv[(((size_t)b * NN + n) << 2) + hidx];
  const float4 bv = *(const float4*)(b2 + ((lane & 15) << 2));
  H4 o;
  o.h[0] = (f16)fmaxf(fmaf((float)acc0[0], invv, bv.x), 0.f);
  o.h[1] = (f16)fmaxf(fmaf((float)acc0[1], invv, bv.y), 0.f);
  o.h[2] = (f16)fmaxf(fmaf((float)acc1[0], invv, bv.z), 0.f);
  o.h[3] = (f16)fmaxf(fmaf((float)acc1[1], invv, bv.w), 0.f);
  *(uint2*)(outh + ((size_t)(b * NN + n) << 9) + (lane << 2)) = o.u;
}

// ---------------- launch ----------------
extern "C" void kernel_launch(void* const* d_in, const int* in_sizes, int n_in,
                              void* d_out, int out_size, void* d_ws, size_t ws_size,
                              hipStream_t stream) {
  const float* sol    = (const float*)d_in[0];
  const float* w      = (const float*)d_in[1];
  const float* fc_w   = (const float*)d_in[2];
  const float* attn_l = (const float*)d_in[3];
  const float* attn_r = (const float*)d_in[4];
  const float* ofc_w  = (const float*)d_in[5];
  const float* ofc_b  = (const float*)d_in[6];
  const float* mlp_w  = (const float*)d_in[7];
  const float* mlp_b  = (const float*)d_in[8];
  const int*   d_src  = (const int*)d_in[9];
  const int*   d_dst  = (const int*)d_in[10];
  float* out = (float*)d_out;

  char* p = (char*)d_ws;
  auto alloc = [&](size_t bytes) { char* r = p; p += (bytes + 255) & ~(size_t)255; return r; };
  f16*   out01h  = (f16*)alloc((size_t)NM * 512 * 2);
  f16*   featWb  = (f16*)alloc((size_t)NM * 256 * 2);      // [b*NN+n][256] row-major
  f16*   fwh     = (f16*)alloc((size_t)ND * ND * 2);
  f16*   alfh    = (f16*)alloc((size_t)16 * ND * 2);       // rows 8-15 zero
  f16*   mlph    = (f16*)alloc((size_t)ND * 512 * 2);
  float* el2     = (float*)alloc((size_t)NT * 4);          // [NN][16]
  float* er2     = (float*)alloc((size_t)NT * 4);
  unsigned* exsp = (unsigned*)alloc((size_t)4 * NE * 4 * 4); // [4][NE][4] splat pairs
  float* sinv    = (float*)alloc((size_t)NT * 4);          // [4][NN][4]
  int*   deg     = (int*)alloc((size_t)(NN + 1) * 4);
  int*   offs    = (int*)alloc((size_t)(NN + 1) * 4);
  int*   cursor  = (int*)alloc((size_t)NN * 4);
  int*   csr_src = (int*)alloc((size_t)NE * 4);
  float* csr_w   = (float*)alloc((size_t)NE * 4);
  if ((size_t)(p - (char*)d_ws) > ws_size) return;

  hipMemsetAsync(deg, 0, (size_t)NN * 4, stream);
  hipMemsetAsync(cursor, 0, (size_t)NN * 4, stream);
  k_deg<<<NE / 256, 256, 0, stream>>>(d_dst, deg);
  k_scan2<<<1, 1024, 0, stream>>>(deg, offs);
  k_scatter<<<NE / 256, 256, 0, stream>>>(d_src, d_dst, w, offs, cursor, csr_src, csr_w);

  k_cvt4<<<(ND * 512 / 4 + 255) / 256, 256, 0, stream>>>(mlp_w, mlph, ND * 512 / 4);

  for (int l = 0; l < 2; ++l) {
    const float* fcl = fc_w + (size_t)l * ND * ND;
    k_fuse<<<272, 256, 0, stream>>>(fcl, ofc_w + (size_t)l * 64 * 64,
                                    attn_l + (size_t)l * NH * 64, attn_r + (size_t)l * NH * 64,
                                    fwh, alfh);
    if (l == 0) {
      k_gemm_f16<1, 1, 1><<<dim3(NM / 64, ND / 128), 256, 0, stream>>>(
          sol, 128, 256, fwh, nullptr, featWb, 256, alfh, el2, er2);
    } else {
      k_gemm_f16<1, 1, 0><<<dim3(NM / 64, ND / 128), 256, 0, stream>>>(
          out01h, 512, 256, fwh, nullptr, featWb, 256, alfh, el2, er2);
    }
    k_soft<<<NN / 4, 256, 0, stream>>>(csr_src, csr_w, offs, el2, er2, exsp, sinv);
    k_edge6<<<(NN / 4) * 4, 256, 0, stream>>>(featWb, exsp, sinv, csr_src, offs,
                                              ofc_b + (size_t)l * 64, out01h + (l == 0 ? 0 : 256));
  }

  k_gemm_f16<0, 0, 0><<<dim3(NM / 64, ND / 128), 256, 0, stream>>>(
      out01h, 512, 512, mlph, mlp_b, out, 256, nullptr, nullptr, nullptr);
}

// Round 10
// 196.347 us; speedup vs baseline: 4.3319x; 1.0461x over previous
//
#include <hip/hip_runtime.h>
#include <math.h>

#define NN 10000
#define NE 160000
#define NB 4
#define NH 4
#define ND 256
#define NT (NN * 16)        // (n,b,h) triples
#define NM 40000            // GEMM rows (b*NN+n)

typedef _Float16 f16;
typedef _Float16 half8 __attribute__((ext_vector_type(8)));
typedef _Float16 h2 __attribute__((ext_vector_type(2)));
typedef float f32x4 __attribute__((ext_vector_type(4)));

union H4 { uint2 u; f16 h[4]; };
union U2H { unsigned u; h2 h; };
union U4H { uint4 u; h2 h[4]; };

__device__ __forceinline__ void gload_lds16(const void* g, void* l) {
  __builtin_amdgcn_global_load_lds((const __attribute__((address_space(1))) void*)g,
                                   (__attribute__((address_space(3))) void*)l, 16, 0, 0);
}

// ---------------- CSR build ----------------
__global__ __launch_bounds__(256) void k_deg(const int* __restrict__ dst, int* __restrict__ deg) {
  int e = blockIdx.x * 256 + threadIdx.x;
  if (e < NE) atomicAdd(&deg[dst[e]], 1);
}

// 3-barrier scan: 10 elems/thread serial + wave shfl scan + cross-wave combine
__global__ __launch_bounds__(1024) void k_scan2(const int* __restrict__ deg, int* __restrict__ offs) {
  __shared__ int wsum[16];
  __shared__ int wbase[17];
  const int t = threadIdx.x, lane = t & 63, wv = t >> 6;
  int v[10];
  int s = 0;
  if (t < 1000) {
#pragma unroll
    for (int i = 0; i < 10; ++i) { v[i] = deg[t * 10 + i]; s += v[i]; }
  }
  int inc = s;
#pragma unroll
  for (int k = 1; k < 64; k <<= 1) {
    int u = __shfl_up(inc, k);
    if (lane >= k) inc += u;
  }
  if (lane == 63) wsum[wv] = inc;
  __syncthreads();
  if (t == 0) {
    int c = 0;
#pragma unroll
    for (int i = 0; i < 16; ++i) { wbase[i] = c; c += wsum[i]; }
    wbase[16] = c;
    offs[NN] = c;
  }
  __syncthreads();
  if (t < 1000) {
    int c = wbase[wv] + inc - s;   // exclusive base for this thread
#pragma unroll
    for (int i = 0; i < 10; ++i) { offs[t * 10 + i] = c; c += v[i]; }
  }
}

__global__ __launch_bounds__(256) void k_scatter(const int* __restrict__ src, const int* __restrict__ dst,
                                                 const float* __restrict__ w, const int* __restrict__ offs,
                                                 int* __restrict__ cursor, int* __restrict__ csr_src,
                                                 float* __restrict__ csr_w) {
  int e = blockIdx.x * 256 + threadIdx.x;
  if (e < NE) {
    int d = dst[e];
    int slot = offs[d] + atomicAdd(&cursor[d], 1);
    csr_src[slot] = src[e];
    csr_w[slot] = w[e];
  }
}

// ---------------- converters ----------------
__global__ __launch_bounds__(256) void k_cvt4(const float* __restrict__ in, f16* __restrict__ out, int n4) {
  int i = blockIdx.x * 256 + threadIdx.x;
  if (i < n4) {
    float4 v = *(const float4*)(in + (size_t)i * 4);
    H4 h;
    h.h[0] = (f16)v.x; h.h[1] = (f16)v.y; h.h[2] = (f16)v.z; h.h[3] = (f16)v.w;
    *(uint2*)(out + (size_t)i * 4) = h.u;
  }
}

// ---------------- weight fusion (fwh + alfh in one launch) ----------------
__global__ __launch_bounds__(256) void k_fuse(const float* __restrict__ fc_w, const float* __restrict__ ofc_w,
                                              const float* __restrict__ al, const float* __restrict__ ar,
                                              f16* __restrict__ fwh, f16* __restrict__ alfh) {
  int r = blockIdx.x;
  int d = threadIdx.x;
  if (r < 256) {
    int h = r >> 6, o = r & 63;
    float acc = 0.f;
    for (int f = 0; f < 64; ++f)
      acc = fmaf(ofc_w[(o << 6) + f], fc_w[(((h << 6) + f) << 8) + d], acc);
    fwh[(r << 8) + d] = (f16)acc;
  } else {
    int rr = r - 256;
    float acc = 0.f;
    if (rr < 8) {
      int h = rr & 3;
      const float* a = (rr < 4) ? al : ar;
      for (int f = 0; f < 64; ++f)
        acc = fmaf(a[(h << 6) + f], fc_w[(((h << 6) + f) << 8) + d], acc);
    }
    alfh[(rr << 8) + d] = (f16)acc;
  }
}

// ---------------- MFMA fp16 GEMM (+optional el/er fusion, +optional fp32 cvt) ----------------
template<int OUTH, int EL, int CVT>
__global__ __launch_bounds__(256) void k_gemm_f16(
    const void* __restrict__ A, int lda, int K,
    const f16* __restrict__ W,
    const float* __restrict__ bias,
    void* __restrict__ outp, int ldo,
    const f16* __restrict__ alfh, float* __restrict__ el2, float* __restrict__ er2)
{
  __shared__ __align__(16) f16 As[64 * 32];
  __shared__ __align__(16) f16 Bs[128 * 32];
  const int tid = threadIdx.x;
  const int lane = tid & 63;
  const int w = tid >> 6;
  const int wr = w >> 1, wc = w & 1;
  const int ra0 = blockIdx.x * 64;
  const int c0 = blockIdx.y * 128;
  const int l2 = lane >> 2;
  const int lk8 = (lane & 3) * 8;

  f32x4 acc[2][4];
#pragma unroll
  for (int mr = 0; mr < 2; ++mr)
#pragma unroll
    for (int nr = 0; nr < 4; ++nr) acc[mr][nr] = (f32x4)0.f;
  f32x4 accel[2];
  accel[0] = (f32x4)0.f; accel[1] = (f32x4)0.f;
  const bool doEl = EL && (blockIdx.y == 0) && (wc == 0);

  const int fr = lane & 15;
  const int fg = (lane >> 4) * 8;

  for (int k0 = 0; k0 < K; k0 += 32) {
    if (CVT) {
      const float* sf = (const float*)A;
      int ra = ra0 + 16 * w + l2;
      int kk = k0 + lk8;
      const float* ps = (kk < 128) ? sf + (size_t)ra * 128 + kk
                                   : sf + (size_t)(NM + ra) * 128 + (kk - 128);
      float4 p0 = *(const float4*)ps;
      float4 p1 = *(const float4*)(ps + 4);
      half8 hv;
      hv[0] = (f16)p0.x; hv[1] = (f16)p0.y; hv[2] = (f16)p0.z; hv[3] = (f16)p0.w;
      hv[4] = (f16)p1.x; hv[5] = (f16)p1.y; hv[6] = (f16)p1.z; hv[7] = (f16)p1.w;
      *(half8*)(As + w * 512 + (lane << 3)) = hv;
    } else {
      gload_lds16((const f16*)A + (size_t)(ra0 + 16 * w + l2) * lda + k0 + lk8, As + w * 512);
    }
    gload_lds16(W + (size_t)(c0 + 32 * w + l2) * K + k0 + lk8, Bs + w * 1024);
    gload_lds16(W + (size_t)(c0 + 32 * w + 16 + l2) * K + k0 + lk8, Bs + w * 1024 + 512);
    __syncthreads();

    half8 af[2], bf[4];
#pragma unroll
    for (int mr = 0; mr < 2; ++mr)
      af[mr] = *(const half8*)(As + (wr * 32 + mr * 16 + fr) * 32 + fg);
#pragma unroll
    for (int nr = 0; nr < 4; ++nr)
      bf[nr] = *(const half8*)(Bs + (wc * 64 + nr * 16 + fr) * 32 + fg);
#pragma unroll
    for (int mr = 0; mr < 2; ++mr)
#pragma unroll
      for (int nr = 0; nr < 4; ++nr)
        acc[mr][nr] = __builtin_amdgcn_mfma_f32_16x16x32_f16(af[mr], bf[nr], acc[mr][nr], 0, 0, 0);
    if (doEl) {
      half8 bal = *(const half8*)(alfh + fr * 256 + k0 + fg);   // L1-hot 8KB
#pragma unroll
      for (int mr = 0; mr < 2; ++mr)
        accel[mr] = __builtin_amdgcn_mfma_f32_16x16x32_f16(af[mr], bal, accel[mr], 0, 0, 0);
    }
    __syncthreads();
  }

  const int r0 = (lane >> 4) * 4;
#pragma unroll
  for (int nr = 0; nr < 4; ++nr) {
    int col = c0 + wc * 64 + nr * 16 + fr;
    float bv = bias ? bias[col] : 0.f;
#pragma unroll
    for (int mr = 0; mr < 2; ++mr) {
      f32x4 v = acc[mr][nr];
#pragma unroll
      for (int r = 0; r < 4; ++r) {
        int ra = ra0 + wr * 32 + mr * 16 + r0 + r;
        float val = v[r] + bv;
        if (OUTH) ((f16*)outp)[(size_t)ra * ldo + col] = (f16)val;
        else      ((float*)outp)[(size_t)ra * ldo + col] = val;
      }
    }
  }
  if (doEl && fr < 8) {
#pragma unroll
    for (int mr = 0; mr < 2; ++mr) {
#pragma unroll
      for (int r = 0; r < 4; ++r) {
        int ra = ra0 + wr * 32 + mr * 16 + r0 + r;
        int n = ra % NN, b = ra / NN;
        int tb = (n << 4) + (b << 2);
        float val = accel[mr][r];
        if (fr < 4) el2[tb + fr] = val;
        else        er2[tb + (fr - 4)] = val;
      }
    }
  }
}

// ---------------- softmax: one wave per node, all 16 bh in-lane ----------------
__global__ __launch_bounds__(256) void k_soft(
    const int* __restrict__ csr_src, const float* __restrict__ csr_w,
    const int* __restrict__ offs,
    const float* __restrict__ el2, const float* __restrict__ er2,
    unsigned* __restrict__ exsp, float* __restrict__ sinv)
{
  const int t = threadIdx.x;
  const int w = t >> 6, lane = t & 63;
  const int n = blockIdx.x * 4 + w;
  const int bh = lane & 15, es = lane >> 4;
  const int b = bh >> 2, h = bh & 3;
  const int s0 = offs[n], s1 = offs[n + 1];
  const float erv = er2[(n << 4) + bh];

  float m = -INFINITY;
  for (int e = s0 + es; e < s1; e += 4) {
    int src = csr_src[e];
    float x = el2[(src << 4) + bh] + erv;
    x = (x > 0.f) ? x : 0.1f * x;
    m = fmaxf(m, x * csr_w[e]);
  }
  m = fmaxf(m, __shfl_xor(m, 16));
  m = fmaxf(m, __shfl_xor(m, 32));

  float ps = 0.f;
  for (int e = s0 + es; e < s1; e += 4) {
    int src = csr_src[e];
    float x = el2[(src << 4) + bh] + erv;
    x = (x > 0.f) ? x : 0.1f * x;
    float a = __expf(x * csr_w[e] - m);
    f16 ah = (f16)a;
    U2H sp; sp.h[0] = ah; sp.h[1] = ah;
    exsp[(((size_t)b * NE + e) << 2) + h] = sp.u;
    ps += a;
  }
  ps += __shfl_xor(ps, 16);
  ps += __shfl_xor(ps, 32);
  if (es == 0) sinv[(((size_t)b * NN + n) << 2) + h] = (s1 > s0) ? 1.f / ps : 0.f;
}

// ---------------- aggregate: wave per (n,b); half-wave = 1 edge, 8 ch/lane ----------------
// blockIdx.x = chunk*4 + b -> XCD pinning for featW b-slice.
// lanes 0-31 process edge e, lanes 32-63 edge e+1 (2 edges/iter, dwordx4 loads).
// Epilogue: cross-half shfl_xor(32) combine; lanes 0-31 write uint4.
__global__ __launch_bounds__(256) void k_edge7(
    const f16* __restrict__ featW_b, const unsigned* __restrict__ exsp,
    const float* __restrict__ sinv, const int* __restrict__ csr_src,
    const int* __restrict__ offs, const float* __restrict__ b2, f16* __restrict__ outh)
{
  __shared__ __align__(16) unsigned aalp[4][64][4];  // [wave][edge][head] splat pairs
  __shared__ unsigned asrc[4][64];
  const int t = threadIdx.x;
  const int w = t >> 6, lane = t & 63;
  const int b = blockIdx.x & 3;
  const int n = (blockIdx.x >> 2) * 4 + w;
  const int s0 = offs[n], s1 = offs[n + 1];
  const int hl = lane & 31;            // lane within half
  const int eh = lane >> 5;            // which edge of the pair
  const int h8 = hl >> 3;              // head (8 ch/lane)
  const int ch0 = hl << 3;             // first channel owned
  const f16* fW = featW_b + ((size_t)b * NN << 8);
  const unsigned* exb = exsp + ((size_t)b * NE << 2);

  h2 a0 = {(f16)0.f, (f16)0.f}, a1 = a0, a2 = a0, a3 = a0;

  for (int c0 = s0; c0 < s1; c0 += 64) {
    const int csz = min(64, s1 - c0);
    // stage all 64 slots (zero-fill beyond csz -> tail-safe)
    unsigned sv = 0;
    uint4 av = {0u, 0u, 0u, 0u};
    if (lane < csz) {
      sv = (unsigned)csr_src[c0 + lane];
      av = *(const uint4*)(exb + ((size_t)(c0 + lane) << 2));
    }
    asrc[w][lane] = sv;
    *(uint4*)(&aalp[w][lane][0]) = av;
#pragma unroll 2
    for (int e = 0; e < csz; e += 2) {
      const int ee = e + eh;
      unsigned su = asrc[w][ee];                 // per-half broadcast
      U2H al; al.u = aalp[w][ee][h8];            // 8-way broadcast
      U4H fv;
      fv.u = *(const uint4*)(fW + ((size_t)su << 8) + ch0);
      a0 += fv.h[0] * al.h;
      a1 += fv.h[1] * al.h;
      a2 += fv.h[2] * al.h;
      a3 += fv.h[3] * al.h;
    }
  }
  // combine the two half-wave edge streams
  U2H u0, u1, u2, u3;
  u0.h = a0; u1.h = a1; u2.h = a2; u3.h = a3;
  U2H p0, p1, p2, p3;
  p0.u = (unsigned)__shfl_xor((int)u0.u, 32);
  p1.u = (unsigned)__shfl_xor((int)u1.u, 32);
  p2.u = (unsigned)__shfl_xor((int)u2.u, 32);
  p3.u = (unsigned)__shfl_xor((int)u3.u, 32);
  a0 += p0.h; a1 += p1.h; a2 += p2.h; a3 += p3.h;

  if (lane < 32) {
    const float invv = sinv[(((size_t)b * NN + n) << 2) + h8];
    const float4 bv0 = *(const float4*)(b2 + ((hl & 7) << 3));
    const float4 bv1 = *(const float4*)(b2 + ((hl & 7) << 3) + 4);
    H4 o01, o23;
    o01.h[0] = (f16)fmaxf(fmaf((float)a0[0], invv, bv0.x), 0.f);
    o01.h[1] = (f16)fmaxf(fmaf((float)a0[1], invv, bv0.y), 0.f);
    o01.h[2] = (f16)fmaxf(fmaf((float)a1[0], invv, bv0.z), 0.f);
    o01.h[3] = (f16)fmaxf(fmaf((float)a1[1], invv, bv0.w), 0.f);
    o23.h[0] = (f16)fmaxf(fmaf((float)a2[0], invv, bv1.x), 0.f);
    o23.h[1] = (f16)fmaxf(fmaf((float)a2[1], invv, bv1.y), 0.f);
    o23.h[2] = (f16)fmaxf(fmaf((float)a3[0], invv, bv1.z), 0.f);
    o23.h[3] = (f16)fmaxf(fmaf((float)a3[1], invv, bv1.w), 0.f);
    uint4 ov;
    ov.x = o01.u.x; ov.y = o01.u.y; ov.z = o23.u.x; ov.w = o23.u.y;
    *(uint4*)(outh + ((size_t)(b * NN + n) << 9) + ch0) = ov;
  }
}

// ---------------- launch ----------------
extern "C" void kernel_launch(void* const* d_in, const int* in_sizes, int n_in,
                              void* d_out, int out_size, void* d_ws, size_t ws_size,
                              hipStream_t stream) {
  const float* sol    = (const float*)d_in[0];
  const float* w      = (const float*)d_in[1];
  const float* fc_w   = (const float*)d_in[2];
  const float* attn_l = (const float*)d_in[3];
  const float* attn_r = (const float*)d_in[4];
  const float* ofc_w  = (const float*)d_in[5];
  const float* ofc_b  = (const float*)d_in[6];
  const float* mlp_w  = (const float*)d_in[7];
  const float* mlp_b  = (const float*)d_in[8];
  const int*   d_src  = (const int*)d_in[9];
  const int*   d_dst  = (const int*)d_in[10];
  float* out = (float*)d_out;

  char* p = (char*)d_ws;
  auto alloc = [&](size_t bytes) { char* r = p; p += (bytes + 255) & ~(size_t)255; return r; };
  f16*   out01h  = (f16*)alloc((size_t)NM * 512 * 2);
  f16*   featWb  = (f16*)alloc((size_t)NM * 256 * 2);      // [b*NN+n][256] row-major
  f16*   fwh     = (f16*)alloc((size_t)ND * ND * 2);
  f16*   alfh    = (f16*)alloc((size_t)16 * ND * 2);       // rows 8-15 zero
  f16*   mlph    = (f16*)alloc((size_t)ND * 512 * 2);
  float* el2     = (float*)alloc((size_t)NT * 4);          // [NN][16]
  float* er2     = (float*)alloc((size_t)NT * 4);
  unsigned* exsp = (unsigned*)alloc((size_t)4 * NE * 4 * 4 + 4096); // [4][NE][4] + tail pad
  float* sinv    = (float*)alloc((size_t)NT * 4);          // [4][NN][4]
  int*   deg     = (int*)alloc((size_t)(NN + 1) * 4);
  int*   offs    = (int*)alloc((size_t)(NN + 1) * 4);
  int*   cursor  = (int*)alloc((size_t)NN * 4);
  int*   csr_src = (int*)alloc((size_t)NE * 4);
  float* csr_w   = (float*)alloc((size_t)NE * 4);
  if ((size_t)(p - (char*)d_ws) > ws_size) return;

  hipMemsetAsync(deg, 0, (size_t)NN * 4, stream);
  hipMemsetAsync(cursor, 0, (size_t)NN * 4, stream);
  k_deg<<<NE / 256, 256, 0, stream>>>(d_dst, deg);
  k_scan2<<<1, 1024, 0, stream>>>(deg, offs);
  k_scatter<<<NE / 256, 256, 0, stream>>>(d_src, d_dst, w, offs, cursor, csr_src, csr_w);

  k_cvt4<<<(ND * 512 / 4 + 255) / 256, 256, 0, stream>>>(mlp_w, mlph, ND * 512 / 4);

  for (int l = 0; l < 2; ++l) {
    const float* fcl = fc_w + (size_t)l * ND * ND;
    k_fuse<<<272, 256, 0, stream>>>(fcl, ofc_w + (size_t)l * 64 * 64,
                                    attn_l + (size_t)l * NH * 64, attn_r + (size_t)l * NH * 64,
                                    fwh, alfh);
    if (l == 0) {
      k_gemm_f16<1, 1, 1><<<dim3(NM / 64, ND / 128), 256, 0, stream>>>(
          sol, 128, 256, fwh, nullptr, featWb, 256, alfh, el2, er2);
    } else {
      k_gemm_f16<1, 1, 0><<<dim3(NM / 64, ND / 128), 256, 0, stream>>>(
          out01h, 512, 256, fwh, nullptr, featWb, 256, alfh, el2, er2);
    }
    k_soft<<<NN / 4, 256, 0, stream>>>(csr_src, csr_w, offs, el2, er2, exsp, sinv);
    k_edge7<<<(NN / 4) * 4, 256, 0, stream>>>(featWb, exsp, sinv, csr_src, offs,
                                              ofc_b + (size_t)l * 64, out01h + (l == 0 ? 0 : 256));
  }

  k_gemm_f16<0, 0, 0><<<dim3(NM / 64, ND / 128), 256, 0, stream>>>(
      out01h, 512, 512, mlph, mlp_b, out, 256, nullptr, nullptr, nullptr);
}